// Round 1
// baseline (159.167 us; speedup 1.0000x reference)
//
#include <hip/hip_runtime.h>
#include <hip/hip_bf16.h>
#include <math.h>

#define NN 10000
#define DD 16
#define FF 256

// pre layout in ws (floats): [0:256) v_tgt, [256:512) u1, [512:768) u2, [768] c0
__global__ __launch_bounds__(256) void k_precomp(
    const float* __restrict__ Wp, const float* __restrict__ Wa,
    const float* __restrict__ ba, const float* __restrict__ a_src,
    const float* __restrict__ a_tgt, float* __restrict__ pre) {
  __shared__ float w1[FF], w2[FF];
  int t = threadIdx.x;
  float s1 = 0.f, s2 = 0.f, vt = 0.f;
  for (int f = 0; f < FF; ++f) {
    float as = a_src[f];
    s1 += as * Wa[f * 2 * FF + t];        // w1[t] = sum_f a_src[f] Wa[f, t]
    s2 += as * Wa[f * 2 * FF + FF + t];   // w2[t] = sum_f a_src[f] Wa[f, F+t]
    vt += a_tgt[f] * Wp[f * FF + t];      // v_tgt[t] = sum_g a_tgt[g] Wp[g, t]
  }
  w1[t] = s1; w2[t] = s2;
  pre[t] = vt;
  __syncthreads();
  float u1 = 0.f, u2 = 0.f;
  for (int g = 0; g < FF; ++g) {
    float wpg = Wp[g * FF + t];
    u1 += w1[g] * wpg;                    // u1[t] = sum_g w1[g] Wp[g, t]
    u2 += w2[g] * wpg;
  }
  pre[FF + t] = u1;
  pre[2 * FF + t] = u2;
  if (t == 0) {
    float c0 = 0.f;
    for (int f = 0; f < FF; ++f) c0 += ba[f] * a_src[f];
    pre[3 * FF] = c0;
  }
}

// One block per node. Computes attention over D=16 neighbors and writes
// agg[n,f] = sum_d attn[d] * neighbors[n,d,f] into out (later projected).
__global__ __launch_bounds__(256) void k_attn_agg(
    const float* __restrict__ nodes, const float* __restrict__ neighbors,
    const float* __restrict__ aspects, const float* __restrict__ pre,
    float* __restrict__ agg) {
  const int n = blockIdx.x;
  const int tid = threadIdx.x;
  const int wid = tid >> 6;
  const int lane = tid & 63;

  __shared__ float nb[DD][FF];   // 16 KB staged neighbor rows
  __shared__ float sc[DD];       // raw scores

  const float4* u1p = (const float4*)(pre + FF);
  const float4* u2p = (const float4*)(pre + 2 * FF);
  const float4* vtp = (const float4*)(pre);
  const float4 u1v = u1p[lane];
  const float4 u2v = u2p[lane];
  const float4 vtv = vtp[lane];
  const float c0 = pre[3 * FF];

  // scores_target (computed redundantly per wave, avoids a sync)
  const float4* ndp = (const float4*)(nodes + (size_t)n * FF);
  float4 nv = ndp[lane];
  float st = nv.x * vtv.x + nv.y * vtv.y + nv.z * vtv.z + nv.w * vtv.w;
  #pragma unroll
  for (int o = 32; o > 0; o >>= 1) st += __shfl_xor(st, o);

  // per-row dots: each wave owns rows {wid, wid+4, wid+8, wid+12}
  const float4* nbg = (const float4*)(neighbors + (size_t)n * DD * FF);
  const float4* asg = (const float4*)(aspects + (size_t)n * DD * FF);
  #pragma unroll
  for (int rr = 0; rr < DD / 4; ++rr) {
    const int r = wid + rr * 4;
    float4 nb4 = nbg[r * (FF / 4) + lane];
    float4 as4 = asg[r * (FF / 4) + lane];
    ((float4*)&nb[r][0])[lane] = nb4;  // stage for agg phase
    float s = nb4.x * u1v.x + nb4.y * u1v.y + nb4.z * u1v.z + nb4.w * u1v.w
            + as4.x * u2v.x + as4.y * u2v.y + as4.z * u2v.z + as4.w * u2v.w;
    #pragma unroll
    for (int o = 32; o > 0; o >>= 1) s += __shfl_xor(s, o);
    if (lane == 0) sc[r] = s + st + c0;
  }
  __syncthreads();

  // softmax over D (raw exp / (sum + 1e-16)), redundantly per thread
  float e[DD];
  float esum = 0.f;
  #pragma unroll
  for (int d = 0; d < DD; ++d) {
    float s = sc[d];
    s = s > 0.f ? s : 0.2f * s;          // leaky_relu(0.2)
    float ev = __expf(s);
    e[d] = ev;
    esum += ev;
  }
  const float inv = 1.f / (esum + 1e-16f);

  // agg: thread t owns feature t
  float acc = 0.f;
  #pragma unroll
  for (int d = 0; d < DD; ++d) acc += e[d] * nb[d][tid];
  agg[(size_t)n * FF + tid] = acc * inv;
}

// In-place: out currently holds agg[N,F]; produce elu(agg @ Wp.T + bias).
#define TN 16
__global__ __launch_bounds__(256) void k_proj_out(
    const float* __restrict__ Wp, const float* __restrict__ bias,
    float* __restrict__ out) {
  const int t = threadIdx.x;
  const int n0 = blockIdx.x * TN;
  __shared__ float ag[TN][FF];  // 16 KB

  #pragma unroll
  for (int i = 0; i < TN; ++i)
    ag[i][t] = out[(size_t)(n0 + i) * FF + t];
  __syncthreads();

  float acc[TN];
  #pragma unroll
  for (int i = 0; i < TN; ++i) acc[i] = 0.f;

  const float4* wrow = (const float4*)(Wp + (size_t)t * FF);
  for (int f4 = 0; f4 < FF / 4; ++f4) {
    float4 w = wrow[f4];
    #pragma unroll
    for (int i = 0; i < TN; ++i) {
      float4 a = ((const float4*)&ag[i][0])[f4];  // LDS broadcast
      acc[i] += a.x * w.x + a.y * w.y + a.z * w.z + a.w * w.w;
    }
  }

  const float b = bias[t];
  #pragma unroll
  for (int i = 0; i < TN; ++i) {
    float v = acc[i] + b;
    out[(size_t)(n0 + i) * FF + t] = v > 0.f ? v : expm1f(v);  // elu
  }
}

extern "C" void kernel_launch(void* const* d_in, const int* in_sizes, int n_in,
                              void* d_out, int out_size, void* d_ws, size_t ws_size,
                              hipStream_t stream) {
  const float* nodes     = (const float*)d_in[0];
  const float* neighbors = (const float*)d_in[1];
  const float* aspects   = (const float*)d_in[2];
  const float* Wp        = (const float*)d_in[3];
  const float* Wa        = (const float*)d_in[4];
  const float* ba        = (const float*)d_in[5];
  const float* a_src     = (const float*)d_in[6];
  const float* a_tgt     = (const float*)d_in[7];
  const float* bias      = (const float*)d_in[8];
  float* out = (float*)d_out;
  float* pre = (float*)d_ws;

  k_precomp<<<1, 256, 0, stream>>>(Wp, Wa, ba, a_src, a_tgt, pre);
  k_attn_agg<<<NN, 256, 0, stream>>>(nodes, neighbors, aspects, pre, out);
  k_proj_out<<<NN / TN, 256, 0, stream>>>(Wp, bias, out);
}

// Round 2
// 137.572 us; speedup vs baseline: 1.1570x; 1.1570x over previous
//
#include <hip/hip_runtime.h>
#include <hip/hip_bf16.h>
#include <math.h>

#define NN 10000
#define DD 16
#define FF 256

// pre layout in ws (floats): [0:256) v_tgt, [256:512) u1, [512:768) u2, [768] c0
__global__ __launch_bounds__(1024) void k_precomp(
    const float* __restrict__ Wp, const float* __restrict__ Wa,
    const float* __restrict__ ba, const float* __restrict__ a_src,
    const float* __restrict__ a_tgt, float* __restrict__ pre) {
  __shared__ float part0[4][FF], part1[4][FF], part2[4][FF];
  __shared__ float w1[FF], w2[FF];
  const int t = threadIdx.x & 255;   // output element
  const int c = threadIdx.x >> 8;    // f-chunk 0..3

  // c0 = ba . a_src (wave 0 only, overlapped with stage-1 loads)
  if (threadIdx.x < 64) {
    const int l = threadIdx.x;
    float cp = 0.f;
    #pragma unroll
    for (int k = 0; k < 4; ++k) cp += ba[l + 64 * k] * a_src[l + 64 * k];
    #pragma unroll
    for (int o = 32; o > 0; o >>= 1) cp += __shfl_xor(cp, o);
    if (l == 0) pre[3 * FF] = cp;
  }

  // stage 1: w1[t]=sum_f a_src[f]Wa[f,t]; w2[t]=sum_f a_src[f]Wa[f,F+t];
  //          vt[t]=sum_g a_tgt[g]Wp[g,t]   (each chunk does 64 f's)
  float s1 = 0.f, s2 = 0.f, vt = 0.f;
  #pragma unroll 8
  for (int f = 64 * c; f < 64 * c + 64; ++f) {
    float as = a_src[f];
    s1 += as * Wa[f * 2 * FF + t];
    s2 += as * Wa[f * 2 * FF + FF + t];
    vt += a_tgt[f] * Wp[f * FF + t];
  }
  part0[c][t] = s1; part1[c][t] = s2; part2[c][t] = vt;
  __syncthreads();
  if (c == 0) {
    w1[t] = part0[0][t] + part0[1][t] + part0[2][t] + part0[3][t];
    w2[t] = part1[0][t] + part1[1][t] + part1[2][t] + part1[3][t];
    pre[t] = part2[0][t] + part2[1][t] + part2[2][t] + part2[3][t];
  }
  __syncthreads();

  // stage 2: u1[t]=sum_g w1[g]Wp[g,t]; u2[t]=sum_g w2[g]Wp[g,t]
  float u1 = 0.f, u2 = 0.f;
  #pragma unroll 8
  for (int g = 64 * c; g < 64 * c + 64; ++g) {
    float wpg = Wp[g * FF + t];
    u1 += w1[g] * wpg;
    u2 += w2[g] * wpg;
  }
  part0[c][t] = u1; part1[c][t] = u2;
  __syncthreads();
  if (c == 0) {
    pre[FF + t]     = part0[0][t] + part0[1][t] + part0[2][t] + part0[3][t];
    pre[2 * FF + t] = part1[0][t] + part1[1][t] + part1[2][t] + part1[3][t];
  }
}

// One block per node; all 9 float4 global loads issued before any dependent
// compute (MLP), single interleaved 5-value butterfly reduce.
__global__ __launch_bounds__(256) void k_attn_agg(
    const float* __restrict__ nodes, const float* __restrict__ neighbors,
    const float* __restrict__ aspects, const float* __restrict__ pre,
    float* __restrict__ agg) {
  const int n = blockIdx.x;
  const int tid = threadIdx.x;
  const int wid = tid >> 6;
  const int lane = tid & 63;

  __shared__ float nb[DD][FF];   // 16 KB staged neighbor rows
  __shared__ float sc[DD];       // raw scores

  const float4* nbg = (const float4*)(neighbors + (size_t)n * DD * FF);
  const float4* asg = (const float4*)(aspects + (size_t)n * DD * FF);
  const float4* ndp = (const float4*)(nodes + (size_t)n * FF);

  // ---- issue ALL global loads first (9 float4 in flight / thread) ----
  float4 nbv[4], asv[4];
  #pragma unroll
  for (int k = 0; k < 4; ++k) nbv[k] = nbg[(wid + 4 * k) * (FF / 4) + lane];
  #pragma unroll
  for (int k = 0; k < 4; ++k) asv[k] = asg[(wid + 4 * k) * (FF / 4) + lane];
  float4 nv = ndp[lane];

  const float4 u1v = ((const float4*)(pre + FF))[lane];
  const float4 u2v = ((const float4*)(pre + 2 * FF))[lane];
  const float4 vtv = ((const float4*)(pre))[lane];
  const float c0 = pre[3 * FF];

  // stage neighbors to LDS for the agg phase
  #pragma unroll
  for (int k = 0; k < 4; ++k)
    ((float4*)&nb[wid + 4 * k][0])[lane] = nbv[k];

  // per-lane partial scores for this wave's 4 rows + target score
  float p[4];
  #pragma unroll
  for (int k = 0; k < 4; ++k)
    p[k] = nbv[k].x * u1v.x + nbv[k].y * u1v.y + nbv[k].z * u1v.z + nbv[k].w * u1v.w
         + asv[k].x * u2v.x + asv[k].y * u2v.y + asv[k].z * u2v.z + asv[k].w * u2v.w;
  float st = nv.x * vtv.x + nv.y * vtv.y + nv.z * vtv.z + nv.w * vtv.w;

  // interleaved butterfly reduce (5 independent chains hide shfl latency)
  #pragma unroll
  for (int o = 32; o > 0; o >>= 1) {
    p[0] += __shfl_xor(p[0], o);
    p[1] += __shfl_xor(p[1], o);
    p[2] += __shfl_xor(p[2], o);
    p[3] += __shfl_xor(p[3], o);
    st   += __shfl_xor(st, o);
  }
  if (lane == 0) {
    #pragma unroll
    for (int k = 0; k < 4; ++k) sc[wid + 4 * k] = p[k] + st + c0;
  }
  __syncthreads();

  // softmax over D (raw exp / (sum + 1e-16)), redundantly per thread
  float e[DD];
  float esum = 0.f;
  #pragma unroll
  for (int d = 0; d < DD; ++d) {
    float s = sc[d];
    s = s > 0.f ? s : 0.2f * s;          // leaky_relu(0.2)
    float ev = __expf(s);
    e[d] = ev;
    esum += ev;
  }
  const float inv = 1.f / (esum + 1e-16f);

  // agg: thread t owns feature t
  float acc = 0.f;
  #pragma unroll
  for (int d = 0; d < DD; ++d) acc += e[d] * nb[d][tid];
  agg[(size_t)n * FF + tid] = acc * inv;
}

// In-place: out currently holds agg[N,F]; produce elu(agg @ Wp.T + bias).
#define TN 16
__global__ __launch_bounds__(256) void k_proj_out(
    const float* __restrict__ Wp, const float* __restrict__ bias,
    float* __restrict__ out) {
  const int t = threadIdx.x;
  const int n0 = blockIdx.x * TN;
  __shared__ float ag[TN][FF];  // 16 KB

  #pragma unroll
  for (int i = 0; i < TN; ++i)
    ag[i][t] = out[(size_t)(n0 + i) * FF + t];
  __syncthreads();

  float acc[TN];
  #pragma unroll
  for (int i = 0; i < TN; ++i) acc[i] = 0.f;

  const float4* wrow = (const float4*)(Wp + (size_t)t * FF);
  for (int f4 = 0; f4 < FF / 4; ++f4) {
    float4 w = wrow[f4];
    #pragma unroll
    for (int i = 0; i < TN; ++i) {
      float4 a = ((const float4*)&ag[i][0])[f4];  // LDS broadcast
      acc[i] += a.x * w.x + a.y * w.y + a.z * w.z + a.w * w.w;
    }
  }

  const float b = bias[t];
  #pragma unroll
  for (int i = 0; i < TN; ++i) {
    float v = acc[i] + b;
    out[(size_t)(n0 + i) * FF + t] = v > 0.f ? v : expm1f(v);  // elu
  }
}

extern "C" void kernel_launch(void* const* d_in, const int* in_sizes, int n_in,
                              void* d_out, int out_size, void* d_ws, size_t ws_size,
                              hipStream_t stream) {
  const float* nodes     = (const float*)d_in[0];
  const float* neighbors = (const float*)d_in[1];
  const float* aspects   = (const float*)d_in[2];
  const float* Wp        = (const float*)d_in[3];
  const float* Wa        = (const float*)d_in[4];
  const float* ba        = (const float*)d_in[5];
  const float* a_src     = (const float*)d_in[6];
  const float* a_tgt     = (const float*)d_in[7];
  const float* bias      = (const float*)d_in[8];
  float* out = (float*)d_out;
  float* pre = (float*)d_ws;

  k_precomp<<<1, 1024, 0, stream>>>(Wp, Wa, ba, a_src, a_tgt, pre);
  k_attn_agg<<<NN, 256, 0, stream>>>(nodes, neighbors, aspects, pre, out);
  k_proj_out<<<NN / TN, 256, 0, stream>>>(Wp, bias, out);
}

// Round 3
// 125.211 us; speedup vs baseline: 1.2712x; 1.0987x over previous
//
#include <hip/hip_runtime.h>
#include <hip/hip_bf16.h>
#include <math.h>

#define NN 10000
#define DD 16
#define FF 256

#define DOT4(a, b) ((a).x*(b).x + (a).y*(b).y + (a).z*(b).z + (a).w*(b).w)

// ws layout (floats): [0:256) v_tgt, [256:512) u1, [512:768) u2, [768] c0
// stage-1 partials live in the tail of d_out (read by k_pre2 BEFORE k_attn_agg
// overwrites all of d_out): part[16][3][256] floats.

// ---------------- precomp stage 1: 16 blocks, 16 f's each ----------------
__global__ __launch_bounds__(256) void k_pre1(
    const float* __restrict__ Wp, const float* __restrict__ Wa,
    const float* __restrict__ a_src, const float* __restrict__ a_tgt,
    float* __restrict__ part) {
  const int t = threadIdx.x, b = blockIdx.x;
  float s1 = 0.f, s2 = 0.f, vt = 0.f;
  #pragma unroll
  for (int k = 0; k < 16; ++k) {
    const int f = b * 16 + k;
    const float as = a_src[f];
    s1 += as * Wa[f * 2 * FF + t];        // partial w1[t]
    s2 += as * Wa[f * 2 * FF + FF + t];   // partial w2[t]
    vt += a_tgt[f] * Wp[f * FF + t];      // partial v_tgt[t]
  }
  part[(b * 3 + 0) * FF + t] = s1;
  part[(b * 3 + 1) * FF + t] = s2;
  part[(b * 3 + 2) * FF + t] = vt;
}

// ---------------- precomp stage 2: 8 blocks, 32 output cols each ----------
__global__ __launch_bounds__(256) void k_pre2(
    const float* __restrict__ Wp, const float* __restrict__ ba,
    const float* __restrict__ a_src, const float* __restrict__ part,
    float* __restrict__ pre) {
  __shared__ float w1[FF], w2[FF];
  __shared__ float pu1[8][32], pu2[8][32];
  const int t = threadIdx.x;

  // reduce stage-1 partials (redundantly per block; 32KB, L2-hot)
  float a0 = 0.f, a1 = 0.f, a2 = 0.f;
  #pragma unroll
  for (int b = 0; b < 16; ++b) {
    a0 += part[(b * 3 + 0) * FF + t];
    a1 += part[(b * 3 + 1) * FF + t];
    a2 += part[(b * 3 + 2) * FF + t];
  }
  w1[t] = a0; w2[t] = a1;
  if (blockIdx.x == 0) {
    pre[t] = a2;                           // v_tgt
    if (t < 64) {
      float cp = 0.f;
      #pragma unroll
      for (int k = 0; k < 4; ++k) cp += ba[t + 64 * k] * a_src[t + 64 * k];
      #pragma unroll
      for (int o = 32; o > 0; o >>= 1) cp += __shfl_xor(cp, o);
      if (t == 0) pre[3 * FF] = cp;        // c0
    }
  }
  __syncthreads();

  // stage 2: u1/u2 for this block's 32 columns; 8 g-chunks across threads
  const int tc = t & 31;                   // column within slice
  const int gc = t >> 5;                   // g-chunk 0..7
  const int tt = blockIdx.x * 32 + tc;     // global output column
  float u1 = 0.f, u2 = 0.f;
  #pragma unroll 4
  for (int g = gc * 32; g < gc * 32 + 32; ++g) {
    const float wpg = Wp[g * FF + tt];
    u1 += w1[g] * wpg;
    u2 += w2[g] * wpg;
  }
  pu1[gc][tc] = u1; pu2[gc][tc] = u2;
  __syncthreads();
  if (t < 32) {
    float r1 = 0.f, r2 = 0.f;
    #pragma unroll
    for (int k = 0; k < 8; ++k) { r1 += pu1[k][t]; r2 += pu2[k][t]; }
    pre[FF + blockIdx.x * 32 + t] = r1;
    pre[2 * FF + blockIdx.x * 32 + t] = r2;
  }
}

// ---------------- attention + aggregation: one WAVE per node --------------
// Persistent grid-stride, no LDS, no barriers. 2000 waves x 5 nodes.
__global__ __launch_bounds__(256, 2) void k_attn_agg(
    const float* __restrict__ nodes, const float* __restrict__ neighbors,
    const float* __restrict__ aspects, const float* __restrict__ pre,
    float* __restrict__ agg) {
  const int lane = threadIdx.x & 63;
  const int gwid = (blockIdx.x << 2) + (threadIdx.x >> 6);

  const float4 vtv = ((const float4*)(pre))[lane];
  const float4 u1v = ((const float4*)(pre + FF))[lane];
  const float4 u2v = ((const float4*)(pre + 2 * FF))[lane];
  const float c0 = pre[3 * FF];

  for (int n = gwid; n < NN; n += 2000) {
    const float4* __restrict__ nbg = (const float4*)(neighbors + (size_t)n * DD * FF);
    const float4* __restrict__ asg = (const float4*)(aspects + (size_t)n * DD * FF);

    // all rows into registers (lane l holds cols 4l..4l+3 of each row)
    float4 nbv[DD], asv[DD];
    #pragma unroll
    for (int r = 0; r < DD; ++r) nbv[r] = nbg[r * 64 + lane];
    #pragma unroll
    for (int r = 0; r < DD; ++r) asv[r] = asg[r * 64 + lane];
    const float4 nv = ((const float4*)(nodes + (size_t)n * FF))[lane];

    // per-lane partial scores (16 rows + target), one interleaved butterfly
    float p[DD + 1];
    #pragma unroll
    for (int r = 0; r < DD; ++r)
      p[r] = DOT4(nbv[r], u1v) + DOT4(asv[r], u2v);
    p[DD] = DOT4(nv, vtv);

    #pragma unroll
    for (int o = 32; o > 0; o >>= 1) {
      #pragma unroll
      for (int r = 0; r < DD + 1; ++r) p[r] += __shfl_xor(p[r], o);
    }
    // xor-butterfly: every lane now holds all 17 full sums

    float e[DD], esum = 0.f;
    #pragma unroll
    for (int r = 0; r < DD; ++r) {
      float s = p[r] + p[DD] + c0;
      s = s > 0.f ? s : 0.2f * s;          // leaky_relu(0.2)
      e[r] = __expf(s);
      esum += e[r];
    }
    const float inv = 1.f / (esum + 1e-16f);

    // lane-local attention-weighted sum (no cross-lane needed)
    float4 acc = make_float4(0.f, 0.f, 0.f, 0.f);
    #pragma unroll
    for (int r = 0; r < DD; ++r) {
      acc.x += e[r] * nbv[r].x;
      acc.y += e[r] * nbv[r].y;
      acc.z += e[r] * nbv[r].z;
      acc.w += e[r] * nbv[r].w;
    }
    acc.x *= inv; acc.y *= inv; acc.z *= inv; acc.w *= inv;
    ((float4*)(agg + (size_t)n * FF))[lane] = acc;
  }
}

// In-place: out currently holds agg[N,F]; produce elu(agg @ Wp.T + bias).
#define TN 16
__global__ __launch_bounds__(256) void k_proj_out(
    const float* __restrict__ Wp, const float* __restrict__ bias,
    float* __restrict__ out) {
  const int t = threadIdx.x;
  const int n0 = blockIdx.x * TN;
  __shared__ float ag[TN][FF];  // 16 KB

  #pragma unroll
  for (int i = 0; i < TN; ++i)
    ag[i][t] = out[(size_t)(n0 + i) * FF + t];
  __syncthreads();

  float acc[TN];
  #pragma unroll
  for (int i = 0; i < TN; ++i) acc[i] = 0.f;

  const float4* wrow = (const float4*)(Wp + (size_t)t * FF);
  for (int f4 = 0; f4 < FF / 4; ++f4) {
    float4 w = wrow[f4];
    #pragma unroll
    for (int i = 0; i < TN; ++i) {
      float4 a = ((const float4*)&ag[i][0])[f4];  // LDS broadcast
      acc[i] += a.x * w.x + a.y * w.y + a.z * w.z + a.w * w.w;
    }
  }

  const float b = bias[t];
  #pragma unroll
  for (int i = 0; i < TN; ++i) {
    float v = acc[i] + b;
    out[(size_t)(n0 + i) * FF + t] = v > 0.f ? v : expm1f(v);  // elu
  }
}

extern "C" void kernel_launch(void* const* d_in, const int* in_sizes, int n_in,
                              void* d_out, int out_size, void* d_ws, size_t ws_size,
                              hipStream_t stream) {
  const float* nodes     = (const float*)d_in[0];
  const float* neighbors = (const float*)d_in[1];
  const float* aspects   = (const float*)d_in[2];
  const float* Wp        = (const float*)d_in[3];
  const float* Wa        = (const float*)d_in[4];
  const float* ba        = (const float*)d_in[5];
  const float* a_src     = (const float*)d_in[6];
  const float* a_tgt     = (const float*)d_in[7];
  const float* bias      = (const float*)d_in[8];
  float* out = (float*)d_out;
  float* pre = (float*)d_ws;

  // stage-1 partials parked in the tail of d_out (consumed before attn writes)
  float* part = out + (size_t)NN * FF - 16 * 3 * FF;

  k_pre1<<<16, 256, 0, stream>>>(Wp, Wa, a_src, a_tgt, part);
  k_pre2<<<8, 256, 0, stream>>>(Wp, ba, a_src, part, pre);
  k_attn_agg<<<500, 256, 0, stream>>>(nodes, neighbors, aspects, pre, out);
  k_proj_out<<<NN / TN, 256, 0, stream>>>(Wp, bias, out);
}

// Round 4
// 120.038 us; speedup vs baseline: 1.3260x; 1.0431x over previous
//
#include <hip/hip_runtime.h>
#include <hip/hip_bf16.h>
#include <math.h>

#define NN 10000
#define DD 16
#define FF 256

typedef float f32x4 __attribute__((ext_vector_type(4)));

#define DOT4(a, b) ((a)[0]*(b)[0] + (a)[1]*(b)[1] + (a)[2]*(b)[2] + (a)[3]*(b)[3])

// ws layout (floats): [0:256) v_tgt, [256:512) u1, [512:768) u2, [768] c0
// stage-1 partials live in the tail of d_out (read by k_pre2 BEFORE k_attn_agg
// overwrites all of d_out): part[16][3][256] floats.

// ---------------- precomp stage 1: 16 blocks, 16 f's each ----------------
__global__ __launch_bounds__(256) void k_pre1(
    const float* __restrict__ Wp, const float* __restrict__ Wa,
    const float* __restrict__ a_src, const float* __restrict__ a_tgt,
    float* __restrict__ part) {
  const int t = threadIdx.x, b = blockIdx.x;
  float s1 = 0.f, s2 = 0.f, vt = 0.f;
  #pragma unroll
  for (int k = 0; k < 16; ++k) {
    const int f = b * 16 + k;
    const float as = a_src[f];
    s1 += as * Wa[f * 2 * FF + t];        // partial w1[t]
    s2 += as * Wa[f * 2 * FF + FF + t];   // partial w2[t]
    vt += a_tgt[f] * Wp[f * FF + t];      // partial v_tgt[t]
  }
  part[(b * 3 + 0) * FF + t] = s1;
  part[(b * 3 + 1) * FF + t] = s2;
  part[(b * 3 + 2) * FF + t] = vt;
}

// ---------------- precomp stage 2: 8 blocks, 32 output cols each ----------
__global__ __launch_bounds__(256) void k_pre2(
    const float* __restrict__ Wp, const float* __restrict__ ba,
    const float* __restrict__ a_src, const float* __restrict__ part,
    float* __restrict__ pre) {
  __shared__ float w1[FF], w2[FF];
  __shared__ float pu1[8][32], pu2[8][32];
  const int t = threadIdx.x;

  // reduce stage-1 partials (redundantly per block; 32KB, L2-hot)
  float a0 = 0.f, a1 = 0.f, a2 = 0.f;
  #pragma unroll
  for (int b = 0; b < 16; ++b) {
    a0 += part[(b * 3 + 0) * FF + t];
    a1 += part[(b * 3 + 1) * FF + t];
    a2 += part[(b * 3 + 2) * FF + t];
  }
  w1[t] = a0; w2[t] = a1;
  if (blockIdx.x == 0) {
    pre[t] = a2;                           // v_tgt
    if (t < 64) {
      float cp = 0.f;
      #pragma unroll
      for (int k = 0; k < 4; ++k) cp += ba[t + 64 * k] * a_src[t + 64 * k];
      #pragma unroll
      for (int o = 32; o > 0; o >>= 1) cp += __shfl_xor(cp, o);
      if (t == 0) pre[3 * FF] = cp;        // c0
    }
  }
  __syncthreads();

  // stage 2: u1/u2 for this block's 32 columns; 8 g-chunks across threads
  const int tc = t & 31;                   // column within slice
  const int gc = t >> 5;                   // g-chunk 0..7
  const int tt = blockIdx.x * 32 + tc;     // global output column
  float u1 = 0.f, u2 = 0.f;
  #pragma unroll 4
  for (int g = gc * 32; g < gc * 32 + 32; ++g) {
    const float wpg = Wp[g * FF + tt];
    u1 += w1[g] * wpg;
    u2 += w2[g] * wpg;
  }
  pu1[gc][tc] = u1; pu2[gc][tc] = u2;
  __syncthreads();
  if (t < 32) {
    float r1 = 0.f, r2 = 0.f;
    #pragma unroll
    for (int k = 0; k < 8; ++k) { r1 += pu1[k][t]; r2 += pu2[k][t]; }
    pre[FF + blockIdx.x * 32 + t] = r1;
    pre[2 * FF + blockIdx.x * 32 + t] = r2;
  }
}

// ---------------- attention + aggregation: one WAVE per node --------------
// Persistent grid-stride, no LDS, no barriers. 2000 waves x 5 nodes.
// R4 single-variable change: neighbors/aspects loaded NONTEMPORAL (nt flag,
// no cache allocation) to discriminate "read-path ceiling ~3.1 TB/s" vs
// "L3 hit/miss mix throttles the stream".
__global__ __launch_bounds__(256, 2) void k_attn_agg(
    const float* __restrict__ nodes, const float* __restrict__ neighbors,
    const float* __restrict__ aspects, const float* __restrict__ pre,
    float* __restrict__ agg) {
  const int lane = threadIdx.x & 63;
  const int gwid = (blockIdx.x << 2) + (threadIdx.x >> 6);

  const f32x4 vtv = ((const f32x4*)(pre))[lane];
  const f32x4 u1v = ((const f32x4*)(pre + FF))[lane];
  const f32x4 u2v = ((const f32x4*)(pre + 2 * FF))[lane];
  const float c0 = pre[3 * FF];

  for (int n = gwid; n < NN; n += 2000) {
    const f32x4* __restrict__ nbg = (const f32x4*)(neighbors + (size_t)n * DD * FF);
    const f32x4* __restrict__ asg = (const f32x4*)(aspects + (size_t)n * DD * FF);

    // all rows into registers (lane l holds cols 4l..4l+3 of each row)
    f32x4 nbv[DD], asv[DD];
    #pragma unroll
    for (int r = 0; r < DD; ++r) nbv[r] = __builtin_nontemporal_load(&nbg[r * 64 + lane]);
    #pragma unroll
    for (int r = 0; r < DD; ++r) asv[r] = __builtin_nontemporal_load(&asg[r * 64 + lane]);
    const f32x4 nv = ((const f32x4*)(nodes + (size_t)n * FF))[lane];

    // per-lane partial scores (16 rows + target), one interleaved butterfly
    float p[DD + 1];
    #pragma unroll
    for (int r = 0; r < DD; ++r)
      p[r] = DOT4(nbv[r], u1v) + DOT4(asv[r], u2v);
    p[DD] = DOT4(nv, vtv);

    #pragma unroll
    for (int o = 32; o > 0; o >>= 1) {
      #pragma unroll
      for (int r = 0; r < DD + 1; ++r) p[r] += __shfl_xor(p[r], o);
    }
    // xor-butterfly: every lane now holds all 17 full sums

    float e[DD], esum = 0.f;
    #pragma unroll
    for (int r = 0; r < DD; ++r) {
      float s = p[r] + p[DD] + c0;
      s = s > 0.f ? s : 0.2f * s;          // leaky_relu(0.2)
      e[r] = __expf(s);
      esum += e[r];
    }
    const float inv = 1.f / (esum + 1e-16f);

    // lane-local attention-weighted sum (no cross-lane needed)
    f32x4 acc = (f32x4)(0.f);
    #pragma unroll
    for (int r = 0; r < DD; ++r) {
      acc[0] += e[r] * nbv[r][0];
      acc[1] += e[r] * nbv[r][1];
      acc[2] += e[r] * nbv[r][2];
      acc[3] += e[r] * nbv[r][3];
    }
    acc[0] *= inv; acc[1] *= inv; acc[2] *= inv; acc[3] *= inv;
    ((f32x4*)(agg + (size_t)n * FF))[lane] = acc;
  }
}

// In-place: out currently holds agg[N,F]; produce elu(agg @ Wp.T + bias).
#define TN 16
__global__ __launch_bounds__(256) void k_proj_out(
    const float* __restrict__ Wp, const float* __restrict__ bias,
    float* __restrict__ out) {
  const int t = threadIdx.x;
  const int n0 = blockIdx.x * TN;
  __shared__ float ag[TN][FF];  // 16 KB

  #pragma unroll
  for (int i = 0; i < TN; ++i)
    ag[i][t] = out[(size_t)(n0 + i) * FF + t];
  __syncthreads();

  float acc[TN];
  #pragma unroll
  for (int i = 0; i < TN; ++i) acc[i] = 0.f;

  const float4* wrow = (const float4*)(Wp + (size_t)t * FF);
  for (int f4 = 0; f4 < FF / 4; ++f4) {
    float4 w = wrow[f4];
    #pragma unroll
    for (int i = 0; i < TN; ++i) {
      float4 a = ((const float4*)&ag[i][0])[f4];  // LDS broadcast
      acc[i] += a.x * w.x + a.y * w.y + a.z * w.z + a.w * w.w;
    }
  }

  const float b = bias[t];
  #pragma unroll
  for (int i = 0; i < TN; ++i) {
    float v = acc[i] + b;
    out[(size_t)(n0 + i) * FF + t] = v > 0.f ? v : expm1f(v);  // elu
  }
}

extern "C" void kernel_launch(void* const* d_in, const int* in_sizes, int n_in,
                              void* d_out, int out_size, void* d_ws, size_t ws_size,
                              hipStream_t stream) {
  const float* nodes     = (const float*)d_in[0];
  const float* neighbors = (const float*)d_in[1];
  const float* aspects   = (const float*)d_in[2];
  const float* Wp        = (const float*)d_in[3];
  const float* Wa        = (const float*)d_in[4];
  const float* ba        = (const float*)d_in[5];
  const float* a_src     = (const float*)d_in[6];
  const float* a_tgt     = (const float*)d_in[7];
  const float* bias      = (const float*)d_in[8];
  float* out = (float*)d_out;
  float* pre = (float*)d_ws;

  // stage-1 partials parked in the tail of d_out (consumed before attn writes)
  float* part = out + (size_t)NN * FF - 16 * 3 * FF;

  k_pre1<<<16, 256, 0, stream>>>(Wp, Wa, a_src, a_tgt, part);
  k_pre2<<<8, 256, 0, stream>>>(Wp, ba, a_src, part, pre);
  k_attn_agg<<<500, 256, 0, stream>>>(nodes, neighbors, aspects, pre, out);
  k_proj_out<<<NN / TN, 256, 0, stream>>>(Wp, bias, out);
}

// Round 5
// 119.062 us; speedup vs baseline: 1.3368x; 1.0082x over previous
//
#include <hip/hip_runtime.h>
#include <hip/hip_bf16.h>
#include <math.h>

#define NN 10000
#define DD 16
#define FF 256

typedef float f32x4 __attribute__((ext_vector_type(4)));

#define DOT4(a, b) ((a)[0]*(b)[0] + (a)[1]*(b)[1] + (a)[2]*(b)[2] + (a)[3]*(b)[3])

// ws layout (floats): [0:256) v_tgt, [256:512) u1, [512:768) u2, [768] c0
// stage-1 partials live in the tail of d_out (read by k_pre2 BEFORE k_attn_agg
// overwrites all of d_out): part[16][3][256] floats.

// ---------------- precomp stage 1: 16 blocks, 16 f's each ----------------
__global__ __launch_bounds__(256) void k_pre1(
    const float* __restrict__ Wp, const float* __restrict__ Wa,
    const float* __restrict__ a_src, const float* __restrict__ a_tgt,
    float* __restrict__ part) {
  const int t = threadIdx.x, b = blockIdx.x;
  float s1 = 0.f, s2 = 0.f, vt = 0.f;
  #pragma unroll
  for (int k = 0; k < 16; ++k) {
    const int f = b * 16 + k;
    const float as = a_src[f];
    s1 += as * Wa[f * 2 * FF + t];        // partial w1[t]
    s2 += as * Wa[f * 2 * FF + FF + t];   // partial w2[t]
    vt += a_tgt[f] * Wp[f * FF + t];      // partial v_tgt[t]
  }
  part[(b * 3 + 0) * FF + t] = s1;
  part[(b * 3 + 1) * FF + t] = s2;
  part[(b * 3 + 2) * FF + t] = vt;
}

// ---------------- precomp stage 2: 8 blocks, 32 output cols each ----------
__global__ __launch_bounds__(256) void k_pre2(
    const float* __restrict__ Wp, const float* __restrict__ ba,
    const float* __restrict__ a_src, const float* __restrict__ part,
    float* __restrict__ pre) {
  __shared__ float w1[FF], w2[FF];
  __shared__ float pu1[8][32], pu2[8][32];
  const int t = threadIdx.x;

  // reduce stage-1 partials (redundantly per block; 32KB, L2-hot)
  float a0 = 0.f, a1 = 0.f, a2 = 0.f;
  #pragma unroll
  for (int b = 0; b < 16; ++b) {
    a0 += part[(b * 3 + 0) * FF + t];
    a1 += part[(b * 3 + 1) * FF + t];
    a2 += part[(b * 3 + 2) * FF + t];
  }
  w1[t] = a0; w2[t] = a1;
  if (blockIdx.x == 0) {
    pre[t] = a2;                           // v_tgt
    if (t < 64) {
      float cp = 0.f;
      #pragma unroll
      for (int k = 0; k < 4; ++k) cp += ba[t + 64 * k] * a_src[t + 64 * k];
      #pragma unroll
      for (int o = 32; o > 0; o >>= 1) cp += __shfl_xor(cp, o);
      if (t == 0) pre[3 * FF] = cp;        // c0
    }
  }
  __syncthreads();

  // stage 2: u1/u2 for this block's 32 columns; 8 g-chunks across threads
  const int tc = t & 31;                   // column within slice
  const int gc = t >> 5;                   // g-chunk 0..7
  const int tt = blockIdx.x * 32 + tc;     // global output column
  float u1 = 0.f, u2 = 0.f;
  #pragma unroll 4
  for (int g = gc * 32; g < gc * 32 + 32; ++g) {
    const float wpg = Wp[g * FF + tt];
    u1 += w1[g] * wpg;
    u2 += w2[g] * wpg;
  }
  pu1[gc][tc] = u1; pu2[gc][tc] = u2;
  __syncthreads();
  if (t < 32) {
    float r1 = 0.f, r2 = 0.f;
    #pragma unroll
    for (int k = 0; k < 8; ++k) { r1 += pu1[k][t]; r2 += pu2[k][t]; }
    pre[FF + blockIdx.x * 32 + t] = r1;
    pre[2 * FF + blockIdx.x * 32 + t] = r2;
  }
}

// ---------------- attention + aggregation: one WAVE per node --------------
// R5: exactly one node per wave, 10000 independent waves (2500 blocks).
// No per-wave loop -> no serialized latency chains; max memory-level
// parallelism. Nontemporal loads for the streamed arrays (kept from R4).
__global__ __launch_bounds__(256) void k_attn_agg(
    const float* __restrict__ nodes, const float* __restrict__ neighbors,
    const float* __restrict__ aspects, const float* __restrict__ pre,
    float* __restrict__ agg) {
  const int lane = threadIdx.x & 63;
  const int n = (blockIdx.x << 2) + (threadIdx.x >> 6);

  const f32x4 vtv = ((const f32x4*)(pre))[lane];
  const f32x4 u1v = ((const f32x4*)(pre + FF))[lane];
  const f32x4 u2v = ((const f32x4*)(pre + 2 * FF))[lane];
  const float c0 = pre[3 * FF];

  const f32x4* __restrict__ nbg = (const f32x4*)(neighbors + (size_t)n * DD * FF);
  const f32x4* __restrict__ asg = (const f32x4*)(aspects + (size_t)n * DD * FF);

  // all rows into registers (lane l holds cols 4l..4l+3 of each row)
  f32x4 nbv[DD], asv[DD];
  #pragma unroll
  for (int r = 0; r < DD; ++r) nbv[r] = __builtin_nontemporal_load(&nbg[r * 64 + lane]);
  #pragma unroll
  for (int r = 0; r < DD; ++r) asv[r] = __builtin_nontemporal_load(&asg[r * 64 + lane]);
  const f32x4 nv = ((const f32x4*)(nodes + (size_t)n * FF))[lane];

  // per-lane partial scores (16 rows + target), one interleaved butterfly
  float p[DD + 1];
  #pragma unroll
  for (int r = 0; r < DD; ++r)
    p[r] = DOT4(nbv[r], u1v) + DOT4(asv[r], u2v);
  p[DD] = DOT4(nv, vtv);

  #pragma unroll
  for (int o = 32; o > 0; o >>= 1) {
    #pragma unroll
    for (int r = 0; r < DD + 1; ++r) p[r] += __shfl_xor(p[r], o);
  }
  // xor-butterfly: every lane now holds all 17 full sums

  float e[DD], esum = 0.f;
  #pragma unroll
  for (int r = 0; r < DD; ++r) {
    float s = p[r] + p[DD] + c0;
    s = s > 0.f ? s : 0.2f * s;            // leaky_relu(0.2)
    e[r] = __expf(s);
    esum += e[r];
  }
  const float inv = 1.f / (esum + 1e-16f);

  // lane-local attention-weighted sum (no cross-lane needed)
  f32x4 acc = (f32x4)(0.f);
  #pragma unroll
  for (int r = 0; r < DD; ++r) {
    acc[0] += e[r] * nbv[r][0];
    acc[1] += e[r] * nbv[r][1];
    acc[2] += e[r] * nbv[r][2];
    acc[3] += e[r] * nbv[r][3];
  }
  acc[0] *= inv; acc[1] *= inv; acc[2] *= inv; acc[3] *= inv;
  ((f32x4*)(agg + (size_t)n * FF))[lane] = acc;
}

// In-place: out currently holds agg[N,F]; produce elu(agg @ Wp.T + bias).
#define TN 16
__global__ __launch_bounds__(256) void k_proj_out(
    const float* __restrict__ Wp, const float* __restrict__ bias,
    float* __restrict__ out) {
  const int t = threadIdx.x;
  const int n0 = blockIdx.x * TN;
  __shared__ float ag[TN][FF];  // 16 KB

  #pragma unroll
  for (int i = 0; i < TN; ++i)
    ag[i][t] = out[(size_t)(n0 + i) * FF + t];
  __syncthreads();

  float acc[TN];
  #pragma unroll
  for (int i = 0; i < TN; ++i) acc[i] = 0.f;

  const float4* wrow = (const float4*)(Wp + (size_t)t * FF);
  for (int f4 = 0; f4 < FF / 4; ++f4) {
    float4 w = wrow[f4];
    #pragma unroll
    for (int i = 0; i < TN; ++i) {
      float4 a = ((const float4*)&ag[i][0])[f4];  // LDS broadcast
      acc[i] += a.x * w.x + a.y * w.y + a.z * w.z + a.w * w.w;
    }
  }

  const float b = bias[t];
  #pragma unroll
  for (int i = 0; i < TN; ++i) {
    float v = acc[i] + b;
    out[(size_t)(n0 + i) * FF + t] = v > 0.f ? v : expm1f(v);  // elu
  }
}

extern "C" void kernel_launch(void* const* d_in, const int* in_sizes, int n_in,
                              void* d_out, int out_size, void* d_ws, size_t ws_size,
                              hipStream_t stream) {
  const float* nodes     = (const float*)d_in[0];
  const float* neighbors = (const float*)d_in[1];
  const float* aspects   = (const float*)d_in[2];
  const float* Wp        = (const float*)d_in[3];
  const float* Wa        = (const float*)d_in[4];
  const float* ba        = (const float*)d_in[5];
  const float* a_src     = (const float*)d_in[6];
  const float* a_tgt     = (const float*)d_in[7];
  const float* bias      = (const float*)d_in[8];
  float* out = (float*)d_out;
  float* pre = (float*)d_ws;

  // stage-1 partials parked in the tail of d_out (consumed before attn writes)
  float* part = out + (size_t)NN * FF - 16 * 3 * FF;

  k_pre1<<<16, 256, 0, stream>>>(Wp, Wa, a_src, a_tgt, part);
  k_pre2<<<8, 256, 0, stream>>>(Wp, ba, a_src, part, pre);
  k_attn_agg<<<NN / 4, 256, 0, stream>>>(nodes, neighbors, aspects, pre, out);
  k_proj_out<<<NN / TN, 256, 0, stream>>>(Wp, bias, out);
}

// Round 6
// 116.047 us; speedup vs baseline: 1.3716x; 1.0260x over previous
//
#include <hip/hip_runtime.h>
#include <hip/hip_bf16.h>
#include <math.h>

#define NN 10000
#define DD 16
#define FF 256

typedef float f32x4 __attribute__((ext_vector_type(4)));
#define DOT4(a, b) ((a)[0]*(b)[0] + (a)[1]*(b)[1] + (a)[2]*(b)[2] + (a)[3]*(b)[3])

// ws layout (floats): [0:256) v_tgt, [256:512) u1, [512:768) u2, [768] c0
// stage-1 partials live in the tail of d_out (read by k_pre2 BEFORE k_attn_agg
// overwrites all of d_out): part[16][3][256] floats.

// ---------------- precomp stage 1: 16 blocks, 16 f's each ----------------
__global__ __launch_bounds__(256) void k_pre1(
    const float* __restrict__ Wp, const float* __restrict__ Wa,
    const float* __restrict__ a_src, const float* __restrict__ a_tgt,
    float* __restrict__ part) {
  const int t = threadIdx.x, b = blockIdx.x;
  float s1 = 0.f, s2 = 0.f, vt = 0.f;
  #pragma unroll
  for (int k = 0; k < 16; ++k) {
    const int f = b * 16 + k;
    const float as = a_src[f];
    s1 += as * Wa[f * 2 * FF + t];        // partial w1[t]
    s2 += as * Wa[f * 2 * FF + FF + t];   // partial w2[t]
    vt += a_tgt[f] * Wp[f * FF + t];      // partial v_tgt[t]
  }
  part[(b * 3 + 0) * FF + t] = s1;
  part[(b * 3 + 1) * FF + t] = s2;
  part[(b * 3 + 2) * FF + t] = vt;
}

// ---------------- precomp stage 2: 8 blocks, 32 output cols each ----------
__global__ __launch_bounds__(256) void k_pre2(
    const float* __restrict__ Wp, const float* __restrict__ ba,
    const float* __restrict__ a_src, const float* __restrict__ part,
    float* __restrict__ pre) {
  __shared__ float w1[FF], w2[FF];
  __shared__ float pu1[8][32], pu2[8][32];
  const int t = threadIdx.x;

  float a0 = 0.f, a1 = 0.f, a2 = 0.f;
  #pragma unroll
  for (int b = 0; b < 16; ++b) {
    a0 += part[(b * 3 + 0) * FF + t];
    a1 += part[(b * 3 + 1) * FF + t];
    a2 += part[(b * 3 + 2) * FF + t];
  }
  w1[t] = a0; w2[t] = a1;
  if (blockIdx.x == 0) {
    pre[t] = a2;                           // v_tgt
    if (t < 64) {
      float cp = 0.f;
      #pragma unroll
      for (int k = 0; k < 4; ++k) cp += ba[t + 64 * k] * a_src[t + 64 * k];
      #pragma unroll
      for (int o = 32; o > 0; o >>= 1) cp += __shfl_xor(cp, o);
      if (t == 0) pre[3 * FF] = cp;        // c0
    }
  }
  __syncthreads();

  const int tc = t & 31;                   // column within slice
  const int gc = t >> 5;                   // g-chunk 0..7
  const int tt = blockIdx.x * 32 + tc;     // global output column
  float u1 = 0.f, u2 = 0.f;
  #pragma unroll 4
  for (int g = gc * 32; g < gc * 32 + 32; ++g) {
    const float wpg = Wp[g * FF + tt];
    u1 += w1[g] * wpg;
    u2 += w2[g] * wpg;
  }
  pu1[gc][tc] = u1; pu2[gc][tc] = u2;
  __syncthreads();
  if (t < 32) {
    float r1 = 0.f, r2 = 0.f;
    #pragma unroll
    for (int k = 0; k < 8; ++k) { r1 += pu1[k][t]; r2 += pu2[k][t]; }
    pre[FF + blockIdx.x * 32 + t] = r1;
    pre[2 * FF + blockIdx.x * 32 + t] = r2;
  }
}

// ---------------- attention + aggregation ---------------------------------
// R6: R2's high-occupancy structure (block-per-node, 4 waves, LDS staging,
// VGPR~32 -> ~8 waves/SIMD) + R4's nontemporal loads. Discriminates
// "issue-density/occupancy limit" (H1) vs "~4 TB/s read-path cap" (H2).
__global__ __launch_bounds__(256) void k_attn_agg(
    const float* __restrict__ nodes, const float* __restrict__ neighbors,
    const float* __restrict__ aspects, const float* __restrict__ pre,
    float* __restrict__ agg) {
  const int n = blockIdx.x;
  const int tid = threadIdx.x;
  const int wid = tid >> 6;
  const int lane = tid & 63;

  __shared__ float nb[DD][FF];   // 16 KB staged neighbor rows
  __shared__ float sc[DD];       // raw scores

  const f32x4* nbg = (const f32x4*)(neighbors + (size_t)n * DD * FF);
  const f32x4* asg = (const f32x4*)(aspects + (size_t)n * DD * FF);
  const f32x4* ndp = (const f32x4*)(nodes + (size_t)n * FF);

  // ---- issue all global loads first (nt: no cache allocation) ----
  f32x4 nbv[4], asv[4];
  #pragma unroll
  for (int k = 0; k < 4; ++k)
    nbv[k] = __builtin_nontemporal_load(&nbg[(wid + 4 * k) * (FF / 4) + lane]);
  #pragma unroll
  for (int k = 0; k < 4; ++k)
    asv[k] = __builtin_nontemporal_load(&asg[(wid + 4 * k) * (FF / 4) + lane]);
  f32x4 nv = ndp[lane];

  const f32x4 u1v = ((const f32x4*)(pre + FF))[lane];
  const f32x4 u2v = ((const f32x4*)(pre + 2 * FF))[lane];
  const f32x4 vtv = ((const f32x4*)(pre))[lane];
  const float c0 = pre[3 * FF];

  // stage neighbors to LDS for the agg phase
  #pragma unroll
  for (int k = 0; k < 4; ++k)
    ((f32x4*)&nb[wid + 4 * k][0])[lane] = nbv[k];

  // per-lane partial scores for this wave's 4 rows + target score
  float p[4];
  #pragma unroll
  for (int k = 0; k < 4; ++k)
    p[k] = DOT4(nbv[k], u1v) + DOT4(asv[k], u2v);
  float st = DOT4(nv, vtv);

  #pragma unroll
  for (int o = 32; o > 0; o >>= 1) {
    p[0] += __shfl_xor(p[0], o);
    p[1] += __shfl_xor(p[1], o);
    p[2] += __shfl_xor(p[2], o);
    p[3] += __shfl_xor(p[3], o);
    st   += __shfl_xor(st, o);
  }
  if (lane == 0) {
    #pragma unroll
    for (int k = 0; k < 4; ++k) sc[wid + 4 * k] = p[k] + st + c0;
  }
  __syncthreads();

  // softmax over D (raw exp / (sum + 1e-16)), redundantly per thread
  float e[DD];
  float esum = 0.f;
  #pragma unroll
  for (int d = 0; d < DD; ++d) {
    float s = sc[d];
    s = s > 0.f ? s : 0.2f * s;            // leaky_relu(0.2)
    float ev = __expf(s);
    e[d] = ev;
    esum += ev;
  }
  const float inv = 1.f / (esum + 1e-16f);

  // agg: thread t owns feature t (2-way LDS bank alias only — free)
  float acc = 0.f;
  #pragma unroll
  for (int d = 0; d < DD; ++d) acc += e[d] * nb[d][tid];
  agg[(size_t)n * FF + tid] = acc * inv;
}

// In-place: out currently holds agg[N,F]; produce elu(agg @ Wp.T + bias).
#define TN 16
__global__ __launch_bounds__(256) void k_proj_out(
    const float* __restrict__ Wp, const float* __restrict__ bias,
    float* __restrict__ out) {
  const int t = threadIdx.x;
  const int n0 = blockIdx.x * TN;
  __shared__ float ag[TN][FF];  // 16 KB

  #pragma unroll
  for (int i = 0; i < TN; ++i)
    ag[i][t] = out[(size_t)(n0 + i) * FF + t];
  __syncthreads();

  float acc[TN];
  #pragma unroll
  for (int i = 0; i < TN; ++i) acc[i] = 0.f;

  const float4* wrow = (const float4*)(Wp + (size_t)t * FF);
  for (int f4 = 0; f4 < FF / 4; ++f4) {
    float4 w = wrow[f4];
    #pragma unroll
    for (int i = 0; i < TN; ++i) {
      float4 a = ((const float4*)&ag[i][0])[f4];  // LDS broadcast
      acc[i] += a.x * w.x + a.y * w.y + a.z * w.z + a.w * w.w;
    }
  }

  const float b = bias[t];
  #pragma unroll
  for (int i = 0; i < TN; ++i) {
    float v = acc[i] + b;
    out[(size_t)(n0 + i) * FF + t] = v > 0.f ? v : expm1f(v);  // elu
  }
}

extern "C" void kernel_launch(void* const* d_in, const int* in_sizes, int n_in,
                              void* d_out, int out_size, void* d_ws, size_t ws_size,
                              hipStream_t stream) {
  const float* nodes     = (const float*)d_in[0];
  const float* neighbors = (const float*)d_in[1];
  const float* aspects   = (const float*)d_in[2];
  const float* Wp        = (const float*)d_in[3];
  const float* Wa        = (const float*)d_in[4];
  const float* ba        = (const float*)d_in[5];
  const float* a_src     = (const float*)d_in[6];
  const float* a_tgt     = (const float*)d_in[7];
  const float* bias      = (const float*)d_in[8];
  float* out = (float*)d_out;
  float* pre = (float*)d_ws;

  // stage-1 partials parked in the tail of d_out (consumed before attn writes)
  float* part = out + (size_t)NN * FF - 16 * 3 * FF;

  k_pre1<<<16, 256, 0, stream>>>(Wp, Wa, a_src, a_tgt, part);
  k_pre2<<<8, 256, 0, stream>>>(Wp, ba, a_src, part, pre);
  k_attn_agg<<<NN, 256, 0, stream>>>(nodes, neighbors, aspects, pre, out);
  k_proj_out<<<NN / TN, 256, 0, stream>>>(Wp, bias, out);
}

// Round 7
// 115.517 us; speedup vs baseline: 1.3779x; 1.0046x over previous
//
#include <hip/hip_runtime.h>
#include <hip/hip_bf16.h>
#include <math.h>

#define NN 10000
#define DD 16
#define FF 256

typedef float f32x4 __attribute__((ext_vector_type(4)));
#define DOT4(a, b) ((a)[0]*(b)[0] + (a)[1]*(b)[1] + (a)[2]*(b)[2] + (a)[3]*(b)[3])

// async global->LDS DMA, 16B per lane, NT (no-allocate) cache policy
#define GLOAD_LDS16(gp, lp)                                                 \
  __builtin_amdgcn_global_load_lds(                                         \
      (const __attribute__((address_space(1))) void*)(gp),                  \
      (__attribute__((address_space(3))) void*)(lp), 16, 0, 2)

// ws layout (floats): [0:256) v_tgt, [256:512) u1, [512:768) u2, [768] c0
// stage-1 partials live in the tail of d_out (read by k_pre2 BEFORE k_attn_agg
// overwrites all of d_out): part[16][3][256] floats.

// ---------------- precomp stage 1: 16 blocks, 16 f's each ----------------
__global__ __launch_bounds__(256) void k_pre1(
    const float* __restrict__ Wp, const float* __restrict__ Wa,
    const float* __restrict__ a_src, const float* __restrict__ a_tgt,
    float* __restrict__ part) {
  const int t = threadIdx.x, b = blockIdx.x;
  float s1 = 0.f, s2 = 0.f, vt = 0.f;
  #pragma unroll
  for (int k = 0; k < 16; ++k) {
    const int f = b * 16 + k;
    const float as = a_src[f];
    s1 += as * Wa[f * 2 * FF + t];        // partial w1[t]
    s2 += as * Wa[f * 2 * FF + FF + t];   // partial w2[t]
    vt += a_tgt[f] * Wp[f * FF + t];      // partial v_tgt[t]
  }
  part[(b * 3 + 0) * FF + t] = s1;
  part[(b * 3 + 1) * FF + t] = s2;
  part[(b * 3 + 2) * FF + t] = vt;
}

// ---------------- precomp stage 2: 8 blocks, 32 output cols each ----------
__global__ __launch_bounds__(256) void k_pre2(
    const float* __restrict__ Wp, const float* __restrict__ ba,
    const float* __restrict__ a_src, const float* __restrict__ part,
    float* __restrict__ pre) {
  __shared__ float w1[FF], w2[FF];
  __shared__ float pu1[8][32], pu2[8][32];
  const int t = threadIdx.x;

  float a0 = 0.f, a1 = 0.f, a2 = 0.f;
  #pragma unroll
  for (int b = 0; b < 16; ++b) {
    a0 += part[(b * 3 + 0) * FF + t];
    a1 += part[(b * 3 + 1) * FF + t];
    a2 += part[(b * 3 + 2) * FF + t];
  }
  w1[t] = a0; w2[t] = a1;
  if (blockIdx.x == 0) {
    pre[t] = a2;                           // v_tgt
    if (t < 64) {
      float cp = 0.f;
      #pragma unroll
      for (int k = 0; k < 4; ++k) cp += ba[t + 64 * k] * a_src[t + 64 * k];
      #pragma unroll
      for (int o = 32; o > 0; o >>= 1) cp += __shfl_xor(cp, o);
      if (t == 0) pre[3 * FF] = cp;        // c0
    }
  }
  __syncthreads();

  const int tc = t & 31;                   // column within slice
  const int gc = t >> 5;                   // g-chunk 0..7
  const int tt = blockIdx.x * 32 + tc;     // global output column
  float u1 = 0.f, u2 = 0.f;
  #pragma unroll 4
  for (int g = gc * 32; g < gc * 32 + 32; ++g) {
    const float wpg = Wp[g * FF + tt];
    u1 += w1[g] * wpg;
    u2 += w2[g] * wpg;
  }
  pu1[gc][tc] = u1; pu2[gc][tc] = u2;
  __syncthreads();
  if (t < 32) {
    float r1 = 0.f, r2 = 0.f;
    #pragma unroll
    for (int k = 0; k < 8; ++k) { r1 += pu1[k][t]; r2 += pu2[k][t]; }
    pre[FF + blockIdx.x * 32 + t] = r1;
    pre[2 * FF + blockIdx.x * 32 + t] = r2;
  }
}

// ---------------- attention + aggregation ---------------------------------
// R7 single-variable change vs R6: neighbors/aspects staged to LDS via the
// async global_load_lds DMA path (no VGPR round-trip) instead of nt register
// loads. Tests whether the DMA/LDS-return path has the store-path's
// throughput character (~7 TB/s) vs the VGPR-return read cap (~4 TB/s).
__global__ __launch_bounds__(256) void k_attn_agg(
    const float* __restrict__ nodes, const float* __restrict__ neighbors,
    const float* __restrict__ aspects, const float* __restrict__ pre,
    float* __restrict__ agg) {
  const int n = blockIdx.x;
  const int tid = threadIdx.x;
  const int wid = tid >> 6;
  const int lane = tid & 63;

  __shared__ float nb[DD][FF];   // 16 KB neighbors
  __shared__ float as_[DD][FF];  // 16 KB aspects
  __shared__ float sc[DD];       // raw scores

  const float* nbg = neighbors + (size_t)n * DD * FF;
  const float* asg = aspects + (size_t)n * DD * FF;

  // ---- issue all DMAs (8 per wave: 4 nb rows + 4 as rows) ----
  #pragma unroll
  for (int k = 0; k < 4; ++k) {
    const int r = wid + 4 * k;
    GLOAD_LDS16(nbg + r * FF + lane * 4, &nb[r][0]);
  }
  #pragma unroll
  for (int k = 0; k < 4; ++k) {
    const int r = wid + 4 * k;
    GLOAD_LDS16(asg + r * FF + lane * 4, &as_[r][0]);
  }

  // params + node row while DMAs are in flight
  const f32x4 u1v = ((const f32x4*)(pre + FF))[lane];
  const f32x4 u2v = ((const f32x4*)(pre + 2 * FF))[lane];
  const f32x4 vtv = ((const f32x4*)(pre))[lane];
  const float c0 = pre[3 * FF];
  const f32x4 nv = ((const f32x4*)(nodes + (size_t)n * FF))[lane];

  float st = DOT4(nv, vtv);

  __syncthreads();  // vmcnt(0) drain + barrier: all rows resident in LDS

  // per-lane partial scores for this wave's 4 rows (from LDS, 2-way alias)
  float p[4];
  #pragma unroll
  for (int k = 0; k < 4; ++k) {
    const int r = wid + 4 * k;
    const f32x4 nbr = ((const f32x4*)&nb[r][0])[lane];
    const f32x4 asr = ((const f32x4*)&as_[r][0])[lane];
    p[k] = DOT4(nbr, u1v) + DOT4(asr, u2v);
  }

  #pragma unroll
  for (int o = 32; o > 0; o >>= 1) {
    p[0] += __shfl_xor(p[0], o);
    p[1] += __shfl_xor(p[1], o);
    p[2] += __shfl_xor(p[2], o);
    p[3] += __shfl_xor(p[3], o);
    st   += __shfl_xor(st, o);
  }
  if (lane == 0) {
    #pragma unroll
    for (int k = 0; k < 4; ++k) sc[wid + 4 * k] = p[k] + st + c0;
  }
  __syncthreads();

  // softmax over D (raw exp / (sum + 1e-16)), redundantly per thread
  float e[DD];
  float esum = 0.f;
  #pragma unroll
  for (int d = 0; d < DD; ++d) {
    float s = sc[d];
    s = s > 0.f ? s : 0.2f * s;            // leaky_relu(0.2)
    float ev = __expf(s);
    e[d] = ev;
    esum += ev;
  }
  const float inv = 1.f / (esum + 1e-16f);

  // agg: thread t owns feature t (2-way LDS bank alias only — free)
  float acc = 0.f;
  #pragma unroll
  for (int d = 0; d < DD; ++d) acc += e[d] * nb[d][tid];
  agg[(size_t)n * FF + tid] = acc * inv;
}

// In-place: out currently holds agg[N,F]; produce elu(agg @ Wp.T + bias).
#define TN 16
__global__ __launch_bounds__(256) void k_proj_out(
    const float* __restrict__ Wp, const float* __restrict__ bias,
    float* __restrict__ out) {
  const int t = threadIdx.x;
  const int n0 = blockIdx.x * TN;
  __shared__ float ag[TN][FF];  // 16 KB

  #pragma unroll
  for (int i = 0; i < TN; ++i)
    ag[i][t] = out[(size_t)(n0 + i) * FF + t];
  __syncthreads();

  float acc[TN];
  #pragma unroll
  for (int i = 0; i < TN; ++i) acc[i] = 0.f;

  const float4* wrow = (const float4*)(Wp + (size_t)t * FF);
  for (int f4 = 0; f4 < FF / 4; ++f4) {
    float4 w = wrow[f4];
    #pragma unroll
    for (int i = 0; i < TN; ++i) {
      float4 a = ((const float4*)&ag[i][0])[f4];  // LDS broadcast
      acc[i] += a.x * w.x + a.y * w.y + a.z * w.z + a.w * w.w;
    }
  }

  const float b = bias[t];
  #pragma unroll
  for (int i = 0; i < TN; ++i) {
    float v = acc[i] + b;
    out[(size_t)(n0 + i) * FF + t] = v > 0.f ? v : expm1f(v);  // elu
  }
}

extern "C" void kernel_launch(void* const* d_in, const int* in_sizes, int n_in,
                              void* d_out, int out_size, void* d_ws, size_t ws_size,
                              hipStream_t stream) {
  const float* nodes     = (const float*)d_in[0];
  const float* neighbors = (const float*)d_in[1];
  const float* aspects   = (const float*)d_in[2];
  const float* Wp        = (const float*)d_in[3];
  const float* Wa        = (const float*)d_in[4];
  const float* ba        = (const float*)d_in[5];
  const float* a_src     = (const float*)d_in[6];
  const float* a_tgt     = (const float*)d_in[7];
  const float* bias      = (const float*)d_in[8];
  float* out = (float*)d_out;
  float* pre = (float*)d_ws;

  // stage-1 partials parked in the tail of d_out (consumed before attn writes)
  float* part = out + (size_t)NN * FF - 16 * 3 * FF;

  k_pre1<<<16, 256, 0, stream>>>(Wp, Wa, a_src, a_tgt, part);
  k_pre2<<<8, 256, 0, stream>>>(Wp, ba, a_src, part, pre);
  k_attn_agg<<<NN, 256, 0, stream>>>(nodes, neighbors, aspects, pre, out);
  k_proj_out<<<NN / TN, 256, 0, stream>>>(Wp, bias, out);
}

// Round 8
// 112.833 us; speedup vs baseline: 1.4106x; 1.0238x over previous
//
#include <hip/hip_runtime.h>
#include <hip/hip_bf16.h>
#include <math.h>

#define NN 10000
#define DD 16
#define FF 256
#define TN 16   // nodes per block in the fused kernel

typedef float f32x4 __attribute__((ext_vector_type(4)));
#define DOT4(a, b) ((a)[0]*(b)[0] + (a)[1]*(b)[1] + (a)[2]*(b)[2] + (a)[3]*(b)[3])

// ws layout (floats): [0:256) v_tgt, [256:512) u1, [512:768) u2, [768] c0
// stage-1 partials live in the tail of d_out (read by k_pre2 BEFORE k_fused
// overwrites all of d_out): part[16][3][256] floats.

// ---------------- precomp stage 1: 16 blocks, 16 f's each ----------------
__global__ __launch_bounds__(256) void k_pre1(
    const float* __restrict__ Wp, const float* __restrict__ Wa,
    const float* __restrict__ a_src, const float* __restrict__ a_tgt,
    float* __restrict__ part) {
  const int t = threadIdx.x, b = blockIdx.x;
  float s1 = 0.f, s2 = 0.f, vt = 0.f;
  #pragma unroll
  for (int k = 0; k < 16; ++k) {
    const int f = b * 16 + k;
    const float as = a_src[f];
    s1 += as * Wa[f * 2 * FF + t];        // partial w1[t]
    s2 += as * Wa[f * 2 * FF + FF + t];   // partial w2[t]
    vt += a_tgt[f] * Wp[f * FF + t];      // partial v_tgt[t]
  }
  part[(b * 3 + 0) * FF + t] = s1;
  part[(b * 3 + 1) * FF + t] = s2;
  part[(b * 3 + 2) * FF + t] = vt;
}

// ---------------- precomp stage 2: 8 blocks, 32 output cols each ----------
__global__ __launch_bounds__(256) void k_pre2(
    const float* __restrict__ Wp, const float* __restrict__ ba,
    const float* __restrict__ a_src, const float* __restrict__ part,
    float* __restrict__ pre) {
  __shared__ float w1[FF], w2[FF];
  __shared__ float pu1[8][32], pu2[8][32];
  const int t = threadIdx.x;

  float a0 = 0.f, a1 = 0.f, a2 = 0.f;
  #pragma unroll
  for (int b = 0; b < 16; ++b) {
    a0 += part[(b * 3 + 0) * FF + t];
    a1 += part[(b * 3 + 1) * FF + t];
    a2 += part[(b * 3 + 2) * FF + t];
  }
  w1[t] = a0; w2[t] = a1;
  if (blockIdx.x == 0) {
    pre[t] = a2;                           // v_tgt
    if (t < 64) {
      float cp = 0.f;
      #pragma unroll
      for (int k = 0; k < 4; ++k) cp += ba[t + 64 * k] * a_src[t + 64 * k];
      #pragma unroll
      for (int o = 32; o > 0; o >>= 1) cp += __shfl_xor(cp, o);
      if (t == 0) pre[3 * FF] = cp;        // c0
    }
  }
  __syncthreads();

  const int tc = t & 31;                   // column within slice
  const int gc = t >> 5;                   // g-chunk 0..7
  const int tt = blockIdx.x * 32 + tc;     // global output column
  float u1 = 0.f, u2 = 0.f;
  #pragma unroll 4
  for (int g = gc * 32; g < gc * 32 + 32; ++g) {
    const float wpg = Wp[g * FF + tt];
    u1 += w1[g] * wpg;
    u2 += w2[g] * wpg;
  }
  pu1[gc][tc] = u1; pu2[gc][tc] = u2;
  __syncthreads();
  if (t < 32) {
    float r1 = 0.f, r2 = 0.f;
    #pragma unroll
    for (int k = 0; k < 8; ++k) { r1 += pu1[k][t]; r2 += pu2[k][t]; }
    pre[FF + blockIdx.x * 32 + t] = r1;
    pre[2 * FF + blockIdx.x * 32 + t] = r2;
  }
}

// ---------------- fused attention + aggregation + projection --------------
// R8: one block = 16 nodes. Per node: R6's attn body (nt loads, LDS nb stage,
// butterfly scores, raw-exp softmax, weighted agg) but agg goes to LDS.
// After the loop, the output projection (ex-k_proj_out) runs on the
// LDS-resident agg tile — Wp amortized over 16 nodes, proj VALU overlapped
// with other blocks' HBM streaming, agg HBM round-trip eliminated.
__global__ __launch_bounds__(256) void k_fused(
    const float* __restrict__ nodes, const float* __restrict__ neighbors,
    const float* __restrict__ aspects, const float* __restrict__ pre,
    const float* __restrict__ Wp, const float* __restrict__ bias,
    float* __restrict__ out) {
  const int tid = threadIdx.x;
  const int wid = tid >> 6;
  const int lane = tid & 63;
  const int n0 = blockIdx.x * TN;

  __shared__ float nb[DD][FF];   // 16 KB current node's neighbor rows
  __shared__ float ag[TN][FF];   // 16 KB aggregated rows for this block
  __shared__ float sc[DD];       // raw scores

  const f32x4 u1v = ((const f32x4*)(pre + FF))[lane];
  const f32x4 u2v = ((const f32x4*)(pre + 2 * FF))[lane];
  const f32x4 vtv = ((const f32x4*)(pre))[lane];
  const float c0 = pre[3 * FF];

  for (int i = 0; i < TN; ++i) {
    const int n = n0 + i;
    const f32x4* nbg = (const f32x4*)(neighbors + (size_t)n * DD * FF);
    const f32x4* asg = (const f32x4*)(aspects + (size_t)n * DD * FF);

    // issue all 9 global loads (nt: no cache allocation)
    f32x4 nbv[4], asv[4];
    #pragma unroll
    for (int k = 0; k < 4; ++k)
      nbv[k] = __builtin_nontemporal_load(&nbg[(wid + 4 * k) * (FF / 4) + lane]);
    #pragma unroll
    for (int k = 0; k < 4; ++k)
      asv[k] = __builtin_nontemporal_load(&asg[(wid + 4 * k) * (FF / 4) + lane]);
    const f32x4 nv = ((const f32x4*)(nodes + (size_t)n * FF))[lane];

    // stage neighbors to LDS for the agg step
    #pragma unroll
    for (int k = 0; k < 4; ++k)
      ((f32x4*)&nb[wid + 4 * k][0])[lane] = nbv[k];

    // per-lane partial scores for this wave's 4 rows + target score
    float p[4];
    #pragma unroll
    for (int k = 0; k < 4; ++k)
      p[k] = DOT4(nbv[k], u1v) + DOT4(asv[k], u2v);
    float st = DOT4(nv, vtv);

    #pragma unroll
    for (int o = 32; o > 0; o >>= 1) {
      p[0] += __shfl_xor(p[0], o);
      p[1] += __shfl_xor(p[1], o);
      p[2] += __shfl_xor(p[2], o);
      p[3] += __shfl_xor(p[3], o);
      st   += __shfl_xor(st, o);
    }
    if (lane == 0) {
      #pragma unroll
      for (int k = 0; k < 4; ++k) sc[wid + 4 * k] = p[k] + st + c0;
    }
    __syncthreads();   // sc + nb staging complete

    // softmax over D (raw exp / (sum + 1e-16)), redundantly per thread
    float e[DD];
    float esum = 0.f;
    #pragma unroll
    for (int d = 0; d < DD; ++d) {
      float s = sc[d];
      s = s > 0.f ? s : 0.2f * s;          // leaky_relu(0.2)
      float ev = __expf(s);
      e[d] = ev;
      esum += ev;
    }
    const float inv = 1.f / (esum + 1e-16f);

    // agg into LDS: thread t owns feature t
    float acc = 0.f;
    #pragma unroll
    for (int d = 0; d < DD; ++d) acc += e[d] * nb[d][tid];
    ag[i][tid] = acc * inv;
    __syncthreads();   // protect nb/sc reuse next iteration
  }

  // ---- projection phase: out = elu(ag @ Wp.T + bias), ag LDS-resident ----
  float acc[TN];
  #pragma unroll
  for (int i = 0; i < TN; ++i) acc[i] = 0.f;

  const f32x4* wrow = (const f32x4*)(Wp + (size_t)tid * FF);
  for (int f4 = 0; f4 < FF / 4; ++f4) {
    const f32x4 w = wrow[f4];
    #pragma unroll
    for (int i = 0; i < TN; ++i) {
      const f32x4 a = ((const f32x4*)&ag[i][0])[f4];  // LDS broadcast
      acc[i] += DOT4(a, w);
    }
  }

  const float b = bias[tid];
  #pragma unroll
  for (int i = 0; i < TN; ++i) {
    float v = acc[i] + b;
    out[(size_t)(n0 + i) * FF + tid] = v > 0.f ? v : expm1f(v);  // elu
  }
}

extern "C" void kernel_launch(void* const* d_in, const int* in_sizes, int n_in,
                              void* d_out, int out_size, void* d_ws, size_t ws_size,
                              hipStream_t stream) {
  const float* nodes     = (const float*)d_in[0];
  const float* neighbors = (const float*)d_in[1];
  const float* aspects   = (const float*)d_in[2];
  const float* Wp        = (const float*)d_in[3];
  const float* Wa        = (const float*)d_in[4];
  const float* ba        = (const float*)d_in[5];
  const float* a_src     = (const float*)d_in[6];
  const float* a_tgt     = (const float*)d_in[7];
  const float* bias      = (const float*)d_in[8];
  float* out = (float*)d_out;
  float* pre = (float*)d_ws;

  // stage-1 partials parked in the tail of d_out (consumed before k_fused writes)
  float* part = out + (size_t)NN * FF - 16 * 3 * FF;

  k_pre1<<<16, 256, 0, stream>>>(Wp, Wa, a_src, a_tgt, part);
  k_pre2<<<8, 256, 0, stream>>>(Wp, ba, a_src, part, pre);
  k_fused<<<NN / TN, 256, 0, stream>>>(nodes, neighbors, aspects, pre, Wp, bias, out);
}